// Round 1
// baseline (754.876 us; speedup 1.0000x reference)
//
#include <hip/hip_runtime.h>

#define K2D 26400
#define NFB 1024
#define NBT 80
#define MAXN 13
#define MTOT (NBT * MAXN)   // 1040
#define NA 6
#define NG 5

constexpr int BM = 128, BN = 128, BK = 32;
constexpr int SPLITK = 4;
constexpr int KITERS_TOTAL = K2D / BK;  // 825
constexpr int KCHUNK = 207;             // 207*3 + 204 = 825

typedef __attribute__((ext_vector_type(8))) short     bf16x8;   // 8 bf16 in 4 VGPRs
typedef __attribute__((ext_vector_type(4))) float     f32x4;
typedef __attribute__((ext_vector_type(4))) unsigned short us4;
typedef __attribute__((ext_vector_type(8))) unsigned short us8;

__device__ __forceinline__ unsigned short f2bf(float x) {
    // round-to-nearest-even fp32 -> bf16 (no NaN special-casing needed here)
    unsigned u = __float_as_uint(x);
    u += 0x7fffu + ((u >> 16) & 1u);
    return (unsigned short)(u >> 16);
}

// C_partial[s] += A[rows, kchunk] * W[kchunk, cols]  (bf16 MFMA, fp32 acc)
__global__ __launch_bounds__(256) void gemm_kernel(
    const float* __restrict__ A,   // [1040][26400]
    const float* __restrict__ B,   // [26400][1024]
    float* __restrict__ Cp)        // [SPLITK][1040][1024]
{
    // fragment-packed LDS: [quad][row][8] so frag reads are dense ds_read_b128
    __shared__ __attribute__((aligned(16))) unsigned short Alds[4][BM][8]; // 8 KB
    __shared__ __attribute__((aligned(16))) unsigned short Blds[4][BN][8]; // 8 KB

    const int t = threadIdx.x;
    const int bm = blockIdx.x, bn = blockIdx.y, s = blockIdx.z;
    const int wave = t >> 6, lane = t & 63;
    const int quad = lane >> 4, l16 = lane & 15;
    const int wm = (wave & 1) * 64;    // 2x2 waves, each 64x64
    const int wn = (wave >> 1) * 64;
    const int row0 = bm * BM;
    const int col0 = bn * BN;

    const int it_begin = s * KCHUNK;
    const int it_end   = min(KITERS_TOTAL, it_begin + KCHUNK);

    f32x4 acc[4][4];
#pragma unroll
    for (int i = 0; i < 4; ++i)
#pragma unroll
        for (int j = 0; j < 4; ++j) acc[i][j] = (f32x4){0.f, 0.f, 0.f, 0.f};

    for (int it = it_begin; it < it_end; ++it) {
        const int k0 = it * BK;

        // ---- stage A tile (128x32 fp32 -> bf16), 4 float4/thread, coalesced
#pragma unroll
        for (int i = 0; i < 4; ++i) {
            const int f  = t + i * 256;       // float4 index 0..1023
            const int m  = f >> 3;            // 0..127
            const int kp = (f & 7) * 4;       // 0,4,...,28
            const int gr = row0 + m;
            float4 v = {0.f, 0.f, 0.f, 0.f};
            if (gr < MTOT)
                v = *(const float4*)(A + (size_t)gr * K2D + (k0 + kp));
            us4 u = { f2bf(v.x), f2bf(v.y), f2bf(v.z), f2bf(v.w) };
            *(us4*)(&Alds[kp >> 3][m][kp & 7]) = u;
        }

        // ---- stage B tile (32x128): gather 8 k-contiguous per n (coalesced
        //      across lanes in n), pack -> dense 16B LDS write, no transpose scatter
#pragma unroll
        for (int i = 0; i < 2; ++i) {
            const int p  = t + i * 256;       // 0..511
            const int n  = p & 127;
            const int kq = p >> 7;            // 0..3
            const float* bp = B + (size_t)(k0 + kq * 8) * NFB + (col0 + n);
            us8 u;
#pragma unroll
            for (int j = 0; j < 8; ++j) u[j] = f2bf(bp[(size_t)j * NFB]);
            *(us8*)(&Blds[kq][n][0]) = u;
        }

        __syncthreads();

        bf16x8 af[4], bfr[4];
#pragma unroll
        for (int tm = 0; tm < 4; ++tm)
            af[tm] = *(const bf16x8*)(&Alds[quad][wm + tm * 16 + l16][0]);
#pragma unroll
        for (int tn = 0; tn < 4; ++tn)
            bfr[tn] = *(const bf16x8*)(&Blds[quad][wn + tn * 16 + l16][0]);

#pragma unroll
        for (int tm = 0; tm < 4; ++tm)
#pragma unroll
            for (int tn = 0; tn < 4; ++tn)
                acc[tm][tn] = __builtin_amdgcn_mfma_f32_16x16x32_bf16(
                    af[tm], bfr[tn], acc[tm][tn], 0, 0, 0);

        __syncthreads();
    }

    // ---- store fp32 partials (C/D layout: col = lane&15, row = quad*4 + r)
#pragma unroll
    for (int tm = 0; tm < 4; ++tm) {
        const int rowb = row0 + wm + tm * 16 + quad * 4;
#pragma unroll
        for (int tn = 0; tn < 4; ++tn) {
            const int col = col0 + wn + tn * 16 + l16;
#pragma unroll
            for (int r = 0; r < 4; ++r) {
                const int rr = rowb + r;
                if (rr < MTOT)
                    Cp[((size_t)s * MTOT + rr) * NFB + col] = acc[tm][tn][r];
            }
        }
    }
}

// per-frame: split-K reduce + bias + relu -> h in LDS; action scores (masked),
// masked max-pool, activity scores
__global__ __launch_bounds__(256) void finalize_kernel(
    const float* __restrict__ Cp,
    const float* __restrict__ b_emb,
    const float* __restrict__ w_act,
    const float* __restrict__ b_act,
    const float* __restrict__ w_acty,
    const float* __restrict__ b_acty,
    const int* __restrict__ bboxes_num,
    float* __restrict__ out)
{
    __shared__ __attribute__((aligned(16))) float h[MAXN][NFB]; // 53 KB
    __shared__ float pooled[NFB];                               // 4 KB

    const int bt = blockIdx.x;
    const int t  = threadIdx.x;
    const int Nb = bboxes_num[bt];

    // reduce SPLITK partials, add bias, relu
    for (int i = 0; i < MAXN; ++i) {
        const int flat = i * 256 + t;    // float4 index, 13*256 = 3328 total
        const int row  = flat >> 8;      // 0..12
        const int f4   = flat & 255;
        const size_t base = ((size_t)(bt * MAXN + row)) * NFB + f4 * 4;
        float4 v = *(const float4*)(Cp + base);
#pragma unroll
        for (int s2 = 1; s2 < SPLITK; ++s2) {
            const float4 w = *(const float4*)(Cp + (size_t)s2 * MTOT * NFB + base);
            v.x += w.x; v.y += w.y; v.z += w.z; v.w += w.w;
        }
        const float4 be = *(const float4*)(b_emb + f4 * 4);
        v.x = fmaxf(v.x + be.x, 0.f);
        v.y = fmaxf(v.y + be.y, 0.f);
        v.z = fmaxf(v.z + be.z, 0.f);
        v.w = fmaxf(v.w + be.w, 0.f);
        *(float4*)(&h[row][f4 * 4]) = v;
    }
    __syncthreads();

    const int wave = t >> 6, lane = t & 63;

    // action scores: 13*6 = 78 dot products of length 1024, one wave per dot
    for (int d = wave; d < MAXN * NA; d += 4) {
        const int n = d / NA, a = d % NA;
        float sum = 0.f;
        for (int f = lane; f < NFB; f += 64)
            sum += h[n][f] * w_act[f * NA + a];
#pragma unroll
        for (int o = 32; o > 0; o >>= 1) sum += __shfl_xor(sum, o);
        if (lane == 0)
            out[bt * (MAXN * NA) + d] = (n < Nb) ? (sum + b_act[a]) : 0.f;
    }

    // masked max-pool over valid boxes (h >= 0, Nb >= 1)
    for (int f = t; f < NFB; f += 256) {
        float m = h[0][f];
        for (int n2 = 1; n2 < Nb; ++n2) m = fmaxf(m, h[n2][f]);
        pooled[f] = m;
    }
    __syncthreads();

    // activity scores: 5 dots of length 1024
    for (int g = wave; g < NG; g += 4) {
        float sum = 0.f;
        for (int f = lane; f < NFB; f += 64)
            sum += pooled[f] * w_acty[f * NG + g];
#pragma unroll
        for (int o = 32; o > 0; o >>= 1) sum += __shfl_xor(sum, o);
        if (lane == 0)
            out[NBT * MAXN * NA + bt * NG + g] = sum + b_acty[g];
    }
}

extern "C" void kernel_launch(void* const* d_in, const int* in_sizes, int n_in,
                              void* d_out, int out_size, void* d_ws, size_t ws_size,
                              hipStream_t stream) {
    const float* A       = (const float*)d_in[0];
    const float* W       = (const float*)d_in[1];
    const float* b_emb   = (const float*)d_in[2];
    const float* w_act   = (const float*)d_in[3];
    const float* b_act   = (const float*)d_in[4];
    const float* w_acty  = (const float*)d_in[5];
    const float* b_acty  = (const float*)d_in[6];
    const int*   bboxes  = (const int*)d_in[7];
    float* out = (float*)d_out;
    float* Cp  = (float*)d_ws;   // SPLITK * 1040 * 1024 fp32 = 17.04 MB

    dim3 grid((MTOT + BM - 1) / BM, NFB / BN, SPLITK);  // 9 x 8 x 4 = 288 blocks
    gemm_kernel<<<grid, 256, 0, stream>>>(A, W, Cp);
    finalize_kernel<<<NBT, 256, 0, stream>>>(Cp, b_emb, w_act, b_act, w_acty,
                                             b_acty, bboxes, out);
}

// Round 2
// 503.395 us; speedup vs baseline: 1.4996x; 1.4996x over previous
//
#include <hip/hip_runtime.h>

#define K2D 26400
#define NFB 1024
#define NBT 80
#define MAXN 13
#define MTOT (NBT * MAXN)   // 1040
#define NA 6
#define NG 5
#define KITERS 825          // K2D / 32
#define TILEB 8192          // bytes of one packed 128x32 bf16 tile image
#define MT 9                // M tiles of 128 (1040 -> 9, last padded)
#define NT 8                // N tiles of 128

typedef __attribute__((ext_vector_type(8))) short     bf16x8;
typedef __attribute__((ext_vector_type(4))) float     f32x4;
typedef __attribute__((ext_vector_type(4))) unsigned short us4;
typedef __attribute__((ext_vector_type(8))) unsigned short us8;

__device__ __forceinline__ unsigned short f2bf(float x) {
    unsigned u = __float_as_uint(x);
    u += 0x7fffu + ((u >> 16) & 1u);
    return (unsigned short)(u >> 16);
}

__device__ __forceinline__ void gload_lds16(const void* g, void* l) {
    // 16B per lane; LDS dest = wave-uniform base + lane*16
    __builtin_amdgcn_global_load_lds(
        (const __attribute__((address_space(1))) unsigned int*)g,
        (__attribute__((address_space(3))) unsigned int*)l, 16, 0, 0);
}

// ---- pack A [1040][26400] fp32 -> per-tile bf16 images [bm][it][quad][m][8]
__global__ __launch_bounds__(256) void pack_a(const float* __restrict__ A,
                                              unsigned short* __restrict__ out)
{
    __shared__ __attribute__((aligned(16))) unsigned short T[4][128][8]; // 8 KB
    const int bm = blockIdx.x, it = blockIdx.y;
    const int t = threadIdx.x;
    const int k0 = it * 32;
#pragma unroll
    for (int i = 0; i < 4; ++i) {
        const int f  = t + i * 256;        // float4 slot 0..1023
        const int m  = f >> 3;
        const int kp = (f & 7) * 4;
        const int gr = bm * 128 + m;
        float4 v = {0.f, 0.f, 0.f, 0.f};
        if (gr < MTOT) v = *(const float4*)(A + (size_t)gr * K2D + k0 + kp);
        us4 u = { f2bf(v.x), f2bf(v.y), f2bf(v.z), f2bf(v.w) };
        *(us4*)(&T[kp >> 3][m][kp & 7]) = u;
    }
    __syncthreads();
    us8* o = (us8*)(out + (size_t)(bm * KITERS + it) * (TILEB / 2));
    const us8* s = (const us8*)&T[0][0][0];
#pragma unroll
    for (int i = 0; i < 2; ++i) { const int c = t + i * 256; o[c] = s[c]; }
}

// ---- pack W [26400][1024] fp32 -> per-tile bf16 images [bn][it][quad][n][8]
//      (transpose via padded LDS scratch: conflict-free both directions)
__global__ __launch_bounds__(256) void pack_b(const float* __restrict__ B,
                                              unsigned short* __restrict__ out)
{
    __shared__ float S[32][129]; // 16.5 KB padded
    const int bn = blockIdx.x, it = blockIdx.y;
    const int t = threadIdx.x;
#pragma unroll
    for (int i = 0; i < 4; ++i) {
        const int f  = t + i * 256;        // 0..1023
        const int kr = f >> 5;             // 0..31
        const int n4 = (f & 31) * 4;
        const float4 v = *(const float4*)(B + (size_t)(it * 32 + kr) * NFB + bn * 128 + n4);
        S[kr][n4 + 0] = v.x; S[kr][n4 + 1] = v.y;
        S[kr][n4 + 2] = v.z; S[kr][n4 + 3] = v.w;
    }
    __syncthreads();
    unsigned short* o = out + (size_t)(bn * KITERS + it) * (TILEB / 2);
#pragma unroll
    for (int i = 0; i < 2; ++i) {
        const int c = t + i * 256;         // c = quad*128 + n
        const int n = c & 127, q = c >> 7;
        us8 u;
#pragma unroll
        for (int j = 0; j < 8; ++j) u[j] = f2bf(S[q * 8 + j][n]);
        *(us8*)(o + c * 8) = u;
    }
}

// ---- main GEMM on packed bf16 images: m97 structure (global_load_lds + MFMA)
__global__ __launch_bounds__(256) void gemm_packed(
    const unsigned short* __restrict__ Apack,
    const unsigned short* __restrict__ Bpack,
    float* __restrict__ Cp, int kchunk)
{
    __shared__ __attribute__((aligned(16))) unsigned short Al[4][128][8]; // 8 KB
    __shared__ __attribute__((aligned(16))) unsigned short Bl[4][128][8]; // 8 KB
    const int t = threadIdx.x;
    const int bm = blockIdx.x, bn = blockIdx.y, s = blockIdx.z;
    const int wave = t >> 6, lane = t & 63;
    const int quad = lane >> 4, l16 = lane & 15;
    const int wm = (wave & 1) * 64, wn = (wave >> 1) * 64;
    const int it0 = s * kchunk;
    const int it1 = min(KITERS, it0 + kchunk);

    const char* At = (const char*)Apack + (size_t)(bm * KITERS + it0) * TILEB;
    const char* Bt = (const char*)Bpack + (size_t)(bn * KITERS + it0) * TILEB;

    f32x4 acc[4][4] = {};

    for (int it = it0; it < it1; ++it) {
#pragma unroll
        for (int c = 0; c < 2; ++c) {
            const int off = c * 4096 + wave * 1024 + lane * 16;
            gload_lds16(At + off, (char*)Al + c * 4096 + wave * 1024);
            gload_lds16(Bt + off, (char*)Bl + c * 4096 + wave * 1024);
        }
        __syncthreads();
        bf16x8 af[4], bfr[4];
#pragma unroll
        for (int x = 0; x < 4; ++x) {
            af[x]  = *(const bf16x8*)(&Al[quad][wm + x * 16 + l16][0]);
            bfr[x] = *(const bf16x8*)(&Bl[quad][wn + x * 16 + l16][0]);
        }
#pragma unroll
        for (int x = 0; x < 4; ++x)
#pragma unroll
            for (int y = 0; y < 4; ++y)
                acc[x][y] = __builtin_amdgcn_mfma_f32_16x16x32_bf16(
                    af[x], bfr[y], acc[x][y], 0, 0, 0);
        __syncthreads();
        At += TILEB; Bt += TILEB;
    }

#pragma unroll
    for (int x = 0; x < 4; ++x) {
        const int rowb = bm * 128 + wm + x * 16 + quad * 4;
#pragma unroll
        for (int y = 0; y < 4; ++y) {
            const int col = bn * 128 + wn + y * 16 + l16;
#pragma unroll
            for (int r = 0; r < 4; ++r) {
                const int rr = rowb + r;
                if (rr < MTOT)
                    Cp[((size_t)s * MTOT + rr) * NFB + col] = acc[x][y][r];
            }
        }
    }
}

// ---- fallback GEMM (round-1, fp32 load + convert), used only if ws too small
__global__ __launch_bounds__(256) void gemm_f32(
    const float* __restrict__ A, const float* __restrict__ B,
    float* __restrict__ Cp, int kchunk)
{
    __shared__ __attribute__((aligned(16))) unsigned short Alds[4][128][8];
    __shared__ __attribute__((aligned(16))) unsigned short Blds[4][128][8];
    const int t = threadIdx.x;
    const int bm = blockIdx.x, bn = blockIdx.y, s = blockIdx.z;
    const int wave = t >> 6, lane = t & 63;
    const int quad = lane >> 4, l16 = lane & 15;
    const int wm = (wave & 1) * 64, wn = (wave >> 1) * 64;
    const int row0 = bm * 128, col0 = bn * 128;
    const int it0 = s * kchunk, it1 = min(KITERS, it0 + kchunk);

    f32x4 acc[4][4] = {};
    for (int it = it0; it < it1; ++it) {
        const int k0 = it * 32;
#pragma unroll
        for (int i = 0; i < 4; ++i) {
            const int f = t + i * 256, m = f >> 3, kp = (f & 7) * 4;
            const int gr = row0 + m;
            float4 v = {0.f, 0.f, 0.f, 0.f};
            if (gr < MTOT) v = *(const float4*)(A + (size_t)gr * K2D + k0 + kp);
            us4 u = { f2bf(v.x), f2bf(v.y), f2bf(v.z), f2bf(v.w) };
            *(us4*)(&Alds[kp >> 3][m][kp & 7]) = u;
        }
#pragma unroll
        for (int i = 0; i < 2; ++i) {
            const int p = t + i * 256, n = p & 127, kq = p >> 7;
            const float* bp = B + (size_t)(k0 + kq * 8) * NFB + (col0 + n);
            us8 u;
#pragma unroll
            for (int j = 0; j < 8; ++j) u[j] = f2bf(bp[(size_t)j * NFB]);
            *(us8*)(&Blds[kq][n][0]) = u;
        }
        __syncthreads();
        bf16x8 af[4], bfr[4];
#pragma unroll
        for (int x = 0; x < 4; ++x) {
            af[x]  = *(const bf16x8*)(&Alds[quad][wm + x * 16 + l16][0]);
            bfr[x] = *(const bf16x8*)(&Blds[quad][wn + x * 16 + l16][0]);
        }
#pragma unroll
        for (int x = 0; x < 4; ++x)
#pragma unroll
            for (int y = 0; y < 4; ++y)
                acc[x][y] = __builtin_amdgcn_mfma_f32_16x16x32_bf16(
                    af[x], bfr[y], acc[x][y], 0, 0, 0);
        __syncthreads();
    }
#pragma unroll
    for (int x = 0; x < 4; ++x) {
        const int rowb = row0 + wm + x * 16 + quad * 4;
#pragma unroll
        for (int y = 0; y < 4; ++y) {
            const int col = col0 + wn + y * 16 + l16;
#pragma unroll
            for (int r = 0; r < 4; ++r) {
                const int rr = rowb + r;
                if (rr < MTOT)
                    Cp[((size_t)s * MTOT + rr) * NFB + col] = acc[x][y][r];
            }
        }
    }
}

// ---- per-frame epilogue: split-K reduce + bias + relu, action/activity heads
__global__ __launch_bounds__(256) void finalize_kernel(
    const float* __restrict__ Cp,
    const float* __restrict__ b_emb,
    const float* __restrict__ w_act,
    const float* __restrict__ b_act,
    const float* __restrict__ w_acty,
    const float* __restrict__ b_acty,
    const int* __restrict__ bboxes_num,
    float* __restrict__ out, int splitk)
{
    __shared__ __attribute__((aligned(16))) float h[MAXN][NFB]; // 53 KB
    __shared__ float pooled[NFB];

    const int bt = blockIdx.x;
    const int t  = threadIdx.x;
    const int Nb = bboxes_num[bt];

    for (int i = 0; i < MAXN; ++i) {
        const int flat = i * 256 + t;
        const int row  = flat >> 8;
        const int f4   = flat & 255;
        const size_t base = ((size_t)(bt * MAXN + row)) * NFB + f4 * 4;
        float4 v = *(const float4*)(Cp + base);
        for (int s2 = 1; s2 < splitk; ++s2) {
            const float4 w = *(const float4*)(Cp + (size_t)s2 * MTOT * NFB + base);
            v.x += w.x; v.y += w.y; v.z += w.z; v.w += w.w;
        }
        const float4 be = *(const float4*)(b_emb + f4 * 4);
        v.x = fmaxf(v.x + be.x, 0.f);
        v.y = fmaxf(v.y + be.y, 0.f);
        v.z = fmaxf(v.z + be.z, 0.f);
        v.w = fmaxf(v.w + be.w, 0.f);
        *(float4*)(&h[row][f4 * 4]) = v;
    }
    __syncthreads();

    const int wave = t >> 6, lane = t & 63;

    for (int d = wave; d < MAXN * NA; d += 4) {
        const int n = d / NA, a = d % NA;
        float sum = 0.f;
        for (int f = lane; f < NFB; f += 64)
            sum += h[n][f] * w_act[f * NA + a];
#pragma unroll
        for (int o = 32; o > 0; o >>= 1) sum += __shfl_xor(sum, o);
        if (lane == 0)
            out[bt * (MAXN * NA) + d] = (n < Nb) ? (sum + b_act[a]) : 0.f;
    }

    for (int f = t; f < NFB; f += 256) {
        float m = h[0][f];
        for (int n2 = 1; n2 < Nb; ++n2) m = fmaxf(m, h[n2][f]);
        pooled[f] = m;
    }
    __syncthreads();

    for (int g = wave; g < NG; g += 4) {
        float sum = 0.f;
        for (int f = lane; f < NFB; f += 64)
            sum += pooled[f] * w_acty[f * NG + g];
#pragma unroll
        for (int o = 32; o > 0; o >>= 1) sum += __shfl_xor(sum, o);
        if (lane == 0)
            out[NBT * MAXN * NA + bt * NG + g] = sum + b_acty[g];
    }
}

extern "C" void kernel_launch(void* const* d_in, const int* in_sizes, int n_in,
                              void* d_out, int out_size, void* d_ws, size_t ws_size,
                              hipStream_t stream) {
    const float* A      = (const float*)d_in[0];
    const float* W      = (const float*)d_in[1];
    const float* b_emb  = (const float*)d_in[2];
    const float* w_act  = (const float*)d_in[3];
    const float* b_act  = (const float*)d_in[4];
    const float* w_acty = (const float*)d_in[5];
    const float* b_acty = (const float*)d_in[6];
    const int*   bboxes = (const int*)d_in[7];
    float* out = (float*)d_out;

    const size_t PACKA = (size_t)MT * KITERS * TILEB;   // 60,825,600 B
    const size_t PACKB = (size_t)NT * KITERS * TILEB;   // 54,067,200 B
    const size_t PART  = (size_t)MTOT * NFB * 4;        //  4,259,840 B

    if (ws_size >= PACKA + PACKB + 2 * PART) {
        int splitk = (int)((ws_size - PACKA - PACKB) / PART);
        if (splitk > 16) splitk = 16;
        const int kchunk = (KITERS + splitk - 1) / splitk;
        unsigned short* Ap = (unsigned short*)d_ws;
        unsigned short* Bp = (unsigned short*)((char*)d_ws + PACKA);
        float* Cp = (float*)((char*)d_ws + PACKA + PACKB);

        pack_a<<<dim3(MT, KITERS), 256, 0, stream>>>(A, Ap);
        pack_b<<<dim3(NT, KITERS), 256, 0, stream>>>(W, Bp);
        gemm_packed<<<dim3(MT, NT, splitk), 256, 0, stream>>>(Ap, Bp, Cp, kchunk);
        finalize_kernel<<<NBT, 256, 0, stream>>>(Cp, b_emb, w_act, b_act, w_acty,
                                                 b_acty, bboxes, out, splitk);
    } else {
        // proven round-1 path (needs 17 MB)
        float* Cp = (float*)d_ws;
        gemm_f32<<<dim3(MT, NT, 4), 256, 0, stream>>>(A, W, Cp, 207);
        finalize_kernel<<<NBT, 256, 0, stream>>>(Cp, b_emb, w_act, b_act, w_acty,
                                                 b_acty, bboxes, out, 4);
    }
}

// Round 3
// 448.554 us; speedup vs baseline: 1.6829x; 1.1223x over previous
//
#include <hip/hip_runtime.h>

#define K2D 26400
#define NFB 1024
#define NBT 80
#define MAXN 13
#define MTOT (NBT * MAXN)   // 1040
#define NA 6
#define NG 5
#define KITERS 825          // K2D / 32
#define TILEB 8192          // bytes of one packed 128x32 bf16 tile image
#define MT 9                // M tiles of 128 (1040 -> 9, last padded)
#define NT 8                // N tiles of 128
#define SPLITK 12
#define KCHUNK 69           // 3*ceil(825/(3*12)); 11*69=759, last chunk 66 (both %3==0)

typedef __attribute__((ext_vector_type(8))) short     bf16x8;
typedef __attribute__((ext_vector_type(4))) float     f32x4;
typedef __attribute__((ext_vector_type(4))) unsigned short us4;
typedef __attribute__((ext_vector_type(8))) unsigned short us8;

__device__ __forceinline__ unsigned short f2bf(float x) {
    unsigned u = __float_as_uint(x);
    u += 0x7fffu + ((u >> 16) & 1u);
    return (unsigned short)(u >> 16);
}

__device__ __forceinline__ void gload_lds16(const void* g, void* l) {
    // 16B per lane; LDS dest = wave-uniform base + lane*16
    __builtin_amdgcn_global_load_lds(
        (const __attribute__((address_space(1))) unsigned int*)g,
        (__attribute__((address_space(3))) unsigned int*)l, 16, 0, 0);
}

// ---- pack A [1040][26400] fp32 -> per-tile bf16 images [bm][it][quad][m][8]
__global__ __launch_bounds__(256) void pack_a(const float* __restrict__ A,
                                              unsigned short* __restrict__ out)
{
    __shared__ __attribute__((aligned(16))) unsigned short T[4][128][8]; // 8 KB
    const int bm = blockIdx.x, it = blockIdx.y;
    const int t = threadIdx.x;
    const int k0 = it * 32;
#pragma unroll
    for (int i = 0; i < 4; ++i) {
        const int f  = t + i * 256;
        const int m  = f >> 3;
        const int kp = (f & 7) * 4;
        const int gr = bm * 128 + m;
        float4 v = {0.f, 0.f, 0.f, 0.f};
        if (gr < MTOT) v = *(const float4*)(A + (size_t)gr * K2D + k0 + kp);
        us4 u = { f2bf(v.x), f2bf(v.y), f2bf(v.z), f2bf(v.w) };
        *(us4*)(&T[kp >> 3][m][kp & 7]) = u;
    }
    __syncthreads();
    us8* o = (us8*)(out + (size_t)(bm * KITERS + it) * (TILEB / 2));
    const us8* s = (const us8*)&T[0][0][0];
#pragma unroll
    for (int i = 0; i < 2; ++i) { const int c = t + i * 256; o[c] = s[c]; }
}

// ---- pack W [26400][1024] fp32 -> per-tile bf16 images [bn][it][quad][n][8]
__global__ __launch_bounds__(256) void pack_b(const float* __restrict__ B,
                                              unsigned short* __restrict__ out)
{
    __shared__ float S[32][129]; // padded: conflict-free both directions
    const int bn = blockIdx.x, it = blockIdx.y;
    const int t = threadIdx.x;
#pragma unroll
    for (int i = 0; i < 4; ++i) {
        const int f  = t + i * 256;
        const int kr = f >> 5;
        const int n4 = (f & 31) * 4;
        const float4 v = *(const float4*)(B + (size_t)(it * 32 + kr) * NFB + bn * 128 + n4);
        S[kr][n4 + 0] = v.x; S[kr][n4 + 1] = v.y;
        S[kr][n4 + 2] = v.z; S[kr][n4 + 3] = v.w;
    }
    __syncthreads();
    unsigned short* o = out + (size_t)(bn * KITERS + it) * (TILEB / 2);
#pragma unroll
    for (int i = 0; i < 2; ++i) {
        const int c = t + i * 256;         // c = quad*128 + n
        const int n = c & 127, q = c >> 7;
        us8 u;
#pragma unroll
        for (int j = 0; j < 8; ++j) u[j] = f2bf(S[q * 8 + j][n]);
        *(us8*)(o + c * 8) = u;
    }
}

__device__ __forceinline__ void issue_tile(const char* At, const char* Bt,
                                           char* Al, char* Bl, int wave, int lane) {
#pragma unroll
    for (int c = 0; c < 2; ++c) {
        const int go = c * 4096 + wave * 1024 + lane * 16;
        const int lo = c * 4096 + wave * 1024;
        gload_lds16(At + go, Al + lo);
        gload_lds16(Bt + go, Bl + lo);
    }
}

// ---- pipelined GEMM: 3 LDS buffers, raw s_barrier + s_waitcnt vmcnt(4)
//      invariant: every step issues exactly 4 load-instrs/wave and retires the
//      oldest 4, so vmcnt(4) always means "tile `it` is resident".
__global__ __launch_bounds__(256, 3) void gemm_pipe(
    const unsigned short* __restrict__ Apack,
    const unsigned short* __restrict__ Bpack,
    float* __restrict__ Cp)
{
    __shared__ __attribute__((aligned(16))) unsigned short buf[3][2][4][128][8]; // 48 KB
    const int t = threadIdx.x;
    const int bm = blockIdx.x, bn = blockIdx.y, s = blockIdx.z;
    const int wave = t >> 6, lane = t & 63;
    const int quad = lane >> 4, l16 = lane & 15;
    const int wm = (wave & 1) * 64, wn = (wave >> 1) * 64;
    const int it0 = s * KCHUNK;
    const int it1 = min(KITERS, it0 + KCHUNK);
    const int itlast = it1 - 1;
    const char* Ab = (const char*)Apack + (size_t)bm * KITERS * TILEB;
    const char* Bb = (const char*)Bpack + (size_t)bn * KITERS * TILEB;

    f32x4 acc[4][4] = {};

    // prologue: tiles it0 -> buf0, it0+1 -> buf1  (8 instrs/wave outstanding)
    issue_tile(Ab + (size_t)it0 * TILEB, Bb + (size_t)it0 * TILEB,
               (char*)&buf[0][0], (char*)&buf[0][1], wave, lane);
    const int itp = min(it0 + 1, itlast);
    issue_tile(Ab + (size_t)itp * TILEB, Bb + (size_t)itp * TILEB,
               (char*)&buf[1][0], (char*)&buf[1][1], wave, lane);

#define STEP(ITV, CUR, DST) do {                                               \
    asm volatile("" ::: "memory");                                             \
    __builtin_amdgcn_s_waitcnt(0xF74); /* vmcnt(4), no exp/lgkm wait */        \
    __builtin_amdgcn_s_barrier();                                              \
    asm volatile("" ::: "memory");                                             \
    int itn = (ITV) + 2; itn = itn > itlast ? itlast : itn;                    \
    issue_tile(Ab + (size_t)itn * TILEB, Bb + (size_t)itn * TILEB,             \
               (char*)&buf[DST][0], (char*)&buf[DST][1], wave, lane);          \
    bf16x8 af[4], bfr[4];                                                      \
    _Pragma("unroll")                                                          \
    for (int x = 0; x < 4; ++x) {                                              \
        af[x]  = *(const bf16x8*)(&buf[CUR][0][quad][wm + x * 16 + l16][0]);   \
        bfr[x] = *(const bf16x8*)(&buf[CUR][1][quad][wn + x * 16 + l16][0]);   \
    }                                                                          \
    _Pragma("unroll")                                                          \
    for (int x = 0; x < 4; ++x)                                                \
        _Pragma("unroll")                                                      \
        for (int y = 0; y < 4; ++y)                                            \
            acc[x][y] = __builtin_amdgcn_mfma_f32_16x16x32_bf16(               \
                af[x], bfr[y], acc[x][y], 0, 0, 0);                            \
} while (0)

    for (int it = it0; it < it1; it += 3) {  // chunk lengths 69/66, both %3==0
        STEP(it,     0, 2);
        STEP(it + 1, 1, 0);
        STEP(it + 2, 2, 1);
    }
#undef STEP

#pragma unroll
    for (int x = 0; x < 4; ++x) {
        const int rowb = bm * 128 + wm + x * 16 + quad * 4;
#pragma unroll
        for (int y = 0; y < 4; ++y) {
            const int col = bn * 128 + wn + y * 16 + l16;
#pragma unroll
            for (int r = 0; r < 4; ++r) {
                const int rr = rowb + r;
                if (rr < MTOT)
                    Cp[((size_t)s * MTOT + rr) * NFB + col] = acc[x][y][r];
            }
        }
    }
}

// ---- parallel split-K reduce: one block per row, bias + relu -> h
__global__ __launch_bounds__(256) void reduce_kernel(
    const float* __restrict__ Cp, const float* __restrict__ b_emb,
    float* __restrict__ h)
{
    const int row = blockIdx.x;           // 0..1039
    const int t = threadIdx.x;            // float4 column
    const size_t base = (size_t)row * NFB + t * 4;
    float4 v = *(const float4*)(Cp + base);
#pragma unroll 4
    for (int s2 = 1; s2 < SPLITK; ++s2) {
        const float4 w = *(const float4*)(Cp + (size_t)s2 * MTOT * NFB + base);
        v.x += w.x; v.y += w.y; v.z += w.z; v.w += w.w;
    }
    const float4 be = *(const float4*)(b_emb + t * 4);
    v.x = fmaxf(v.x + be.x, 0.f);
    v.y = fmaxf(v.y + be.y, 0.f);
    v.z = fmaxf(v.z + be.z, 0.f);
    v.w = fmaxf(v.w + be.w, 0.f);
    *(float4*)(h + base) = v;
}

// ---- per-frame heads: action scores (masked), masked max-pool, activities
__global__ __launch_bounds__(256) void heads_kernel(
    const float* __restrict__ h,
    const float* __restrict__ w_act,  const float* __restrict__ b_act,
    const float* __restrict__ w_acty, const float* __restrict__ b_acty,
    const int* __restrict__ bboxes_num, float* __restrict__ out)
{
    __shared__ __attribute__((aligned(16))) float hs[MAXN][NFB]; // 53 KB
    __shared__ float pooled[NFB];
    const int bt = blockIdx.x;
    const int t  = threadIdx.x;
    const int Nb = bboxes_num[bt];

#pragma unroll
    for (int i = 0; i < MAXN; ++i) {
        const float4 v = *(const float4*)(h + ((size_t)(bt * MAXN + i)) * NFB + t * 4);
        *(float4*)(&hs[i][t * 4]) = v;
    }
    __syncthreads();

    const int wave = t >> 6, lane = t & 63;

    for (int d = wave; d < MAXN * NA; d += 4) {
        const int n = d / NA, a = d % NA;
        float sum = 0.f;
        for (int f = lane; f < NFB; f += 64)
            sum += hs[n][f] * w_act[f * NA + a];
#pragma unroll
        for (int o = 32; o > 0; o >>= 1) sum += __shfl_xor(sum, o);
        if (lane == 0)
            out[bt * (MAXN * NA) + d] = (n < Nb) ? (sum + b_act[a]) : 0.f;
    }

    for (int f = t; f < NFB; f += 256) {
        float m = hs[0][f];
        for (int n2 = 1; n2 < Nb; ++n2) m = fmaxf(m, hs[n2][f]);
        pooled[f] = m;
    }
    __syncthreads();

    for (int g = wave; g < NG; g += 4) {
        float sum = 0.f;
        for (int f = lane; f < NFB; f += 64)
            sum += pooled[f] * w_acty[f * NG + g];
#pragma unroll
        for (int o = 32; o > 0; o >>= 1) sum += __shfl_xor(sum, o);
        if (lane == 0)
            out[NBT * MAXN * NA + bt * NG + g] = sum + b_acty[g];
    }
}

// ======== fallback path (round-1 proven), used only if ws too small ========
__global__ __launch_bounds__(256) void gemm_f32(
    const float* __restrict__ A, const float* __restrict__ B,
    float* __restrict__ Cp, int kchunk)
{
    __shared__ __attribute__((aligned(16))) unsigned short Alds[4][128][8];
    __shared__ __attribute__((aligned(16))) unsigned short Blds[4][128][8];
    const int t = threadIdx.x;
    const int bm = blockIdx.x, bn = blockIdx.y, s = blockIdx.z;
    const int wave = t >> 6, lane = t & 63;
    const int quad = lane >> 4, l16 = lane & 15;
    const int wm = (wave & 1) * 64, wn = (wave >> 1) * 64;
    const int row0 = bm * 128, col0 = bn * 128;
    const int it0 = s * kchunk, it1 = min(KITERS, it0 + kchunk);

    f32x4 acc[4][4] = {};
    for (int it = it0; it < it1; ++it) {
        const int k0 = it * 32;
#pragma unroll
        for (int i = 0; i < 4; ++i) {
            const int f = t + i * 256, m = f >> 3, kp = (f & 7) * 4;
            const int gr = row0 + m;
            float4 v = {0.f, 0.f, 0.f, 0.f};
            if (gr < MTOT) v = *(const float4*)(A + (size_t)gr * K2D + k0 + kp);
            us4 u = { f2bf(v.x), f2bf(v.y), f2bf(v.z), f2bf(v.w) };
            *(us4*)(&Alds[kp >> 3][m][kp & 7]) = u;
        }
#pragma unroll
        for (int i = 0; i < 2; ++i) {
            const int p = t + i * 256, n = p & 127, kq = p >> 7;
            const float* bp = B + (size_t)(k0 + kq * 8) * NFB + (col0 + n);
            us8 u;
#pragma unroll
            for (int j = 0; j < 8; ++j) u[j] = f2bf(bp[(size_t)j * NFB]);
            *(us8*)(&Blds[kq][n][0]) = u;
        }
        __syncthreads();
        bf16x8 af[4], bfr[4];
#pragma unroll
        for (int x = 0; x < 4; ++x) {
            af[x]  = *(const bf16x8*)(&Alds[quad][wm + x * 16 + l16][0]);
            bfr[x] = *(const bf16x8*)(&Blds[quad][wn + x * 16 + l16][0]);
        }
#pragma unroll
        for (int x = 0; x < 4; ++x)
#pragma unroll
            for (int y = 0; y < 4; ++y)
                acc[x][y] = __builtin_amdgcn_mfma_f32_16x16x32_bf16(
                    af[x], bfr[y], acc[x][y], 0, 0, 0);
        __syncthreads();
    }
#pragma unroll
    for (int x = 0; x < 4; ++x) {
        const int rowb = row0 + wm + x * 16 + quad * 4;
#pragma unroll
        for (int y = 0; y < 4; ++y) {
            const int col = col0 + wn + y * 16 + l16;
#pragma unroll
            for (int r = 0; r < 4; ++r) {
                const int rr = rowb + r;
                if (rr < MTOT)
                    Cp[((size_t)s * MTOT + rr) * NFB + col] = acc[x][y][r];
            }
        }
    }
}

__global__ __launch_bounds__(256) void finalize_fallback(
    const float* __restrict__ Cp, const float* __restrict__ b_emb,
    const float* __restrict__ w_act, const float* __restrict__ b_act,
    const float* __restrict__ w_acty, const float* __restrict__ b_acty,
    const int* __restrict__ bboxes_num, float* __restrict__ out, int splitk)
{
    __shared__ __attribute__((aligned(16))) float h[MAXN][NFB];
    __shared__ float pooled[NFB];
    const int bt = blockIdx.x;
    const int t  = threadIdx.x;
    const int Nb = bboxes_num[bt];

    for (int i = 0; i < MAXN; ++i) {
        const int flat = i * 256 + t;
        const int row  = flat >> 8;
        const int f4   = flat & 255;
        const size_t base = ((size_t)(bt * MAXN + row)) * NFB + f4 * 4;
        float4 v = *(const float4*)(Cp + base);
        for (int s2 = 1; s2 < splitk; ++s2) {
            const float4 w = *(const float4*)(Cp + (size_t)s2 * MTOT * NFB + base);
            v.x += w.x; v.y += w.y; v.z += w.z; v.w += w.w;
        }
        const float4 be = *(const float4*)(b_emb + f4 * 4);
        v.x = fmaxf(v.x + be.x, 0.f);
        v.y = fmaxf(v.y + be.y, 0.f);
        v.z = fmaxf(v.z + be.z, 0.f);
        v.w = fmaxf(v.w + be.w, 0.f);
        *(float4*)(&h[row][f4 * 4]) = v;
    }
    __syncthreads();
    const int wave = t >> 6, lane = t & 63;
    for (int d = wave; d < MAXN * NA; d += 4) {
        const int n = d / NA, a = d % NA;
        float sum = 0.f;
        for (int f = lane; f < NFB; f += 64)
            sum += h[n][f] * w_act[f * NA + a];
#pragma unroll
        for (int o = 32; o > 0; o >>= 1) sum += __shfl_xor(sum, o);
        if (lane == 0)
            out[bt * (MAXN * NA) + d] = (n < Nb) ? (sum + b_act[a]) : 0.f;
    }
    for (int f = t; f < NFB; f += 256) {
        float m = h[0][f];
        for (int n2 = 1; n2 < Nb; ++n2) m = fmaxf(m, h[n2][f]);
        pooled[f] = m;
    }
    __syncthreads();
    for (int g = wave; g < NG; g += 4) {
        float sum = 0.f;
        for (int f = lane; f < NFB; f += 64)
            sum += pooled[f] * w_acty[f * NG + g];
#pragma unroll
        for (int o = 32; o > 0; o >>= 1) sum += __shfl_xor(sum, o);
        if (lane == 0)
            out[NBT * MAXN * NA + bt * NG + g] = sum + b_acty[g];
    }
}

extern "C" void kernel_launch(void* const* d_in, const int* in_sizes, int n_in,
                              void* d_out, int out_size, void* d_ws, size_t ws_size,
                              hipStream_t stream) {
    const float* A      = (const float*)d_in[0];
    const float* W      = (const float*)d_in[1];
    const float* b_emb  = (const float*)d_in[2];
    const float* w_act  = (const float*)d_in[3];
    const float* b_act  = (const float*)d_in[4];
    const float* w_acty = (const float*)d_in[5];
    const float* b_acty = (const float*)d_in[6];
    const int*   bboxes = (const int*)d_in[7];
    float* out = (float*)d_out;

    const size_t PACKA = (size_t)MT * KITERS * TILEB;   // 60,825,600 B
    const size_t PACKB = (size_t)NT * KITERS * TILEB;   // 54,067,200 B
    const size_t PART  = (size_t)MTOT * NFB * 4;        //  4,259,840 B
    const size_t NEED  = PACKA + PACKB + (SPLITK + 1) * PART;  // ~170.3 MB

    if (ws_size >= NEED) {
        unsigned short* Ap = (unsigned short*)d_ws;
        unsigned short* Bp = (unsigned short*)((char*)d_ws + PACKA);
        float* Cp = (float*)((char*)d_ws + PACKA + PACKB);
        float* h  = (float*)((char*)d_ws + PACKA + PACKB + (size_t)SPLITK * PART);

        pack_a<<<dim3(MT, KITERS), 256, 0, stream>>>(A, Ap);
        pack_b<<<dim3(NT, KITERS), 256, 0, stream>>>(W, Bp);
        gemm_pipe<<<dim3(MT, NT, SPLITK), 256, 0, stream>>>(Ap, Bp, Cp);
        reduce_kernel<<<MTOT, 256, 0, stream>>>(Cp, b_emb, h);
        heads_kernel<<<NBT, 256, 0, stream>>>(h, w_act, b_act, w_acty, b_acty,
                                              bboxes, out);
    } else {
        float* Cp = (float*)d_ws;  // needs 17 MB
        gemm_f32<<<dim3(MT, NT, 4), 256, 0, stream>>>(A, W, Cp, 207);
        finalize_fallback<<<NBT, 256, 0, stream>>>(Cp, b_emb, w_act, b_act,
                                                   w_acty, b_acty, bboxes, out, 4);
    }
}

// Round 4
// 374.160 us; speedup vs baseline: 2.0175x; 1.1988x over previous
//
#include <hip/hip_runtime.h>

#define K2D 26400
#define NFB 1024
#define NBT 80
#define MAXN 13
#define MTOT (NBT * MAXN)   // 1040
#define NA 6
#define NG 5
#define KITERS 825          // K2D / 32
#define TILEB 8192          // bytes of one packed 128x32 bf16 tile image
#define MT128 9             // A pack tiles of 128 rows (covers 1152 >= 1040)
#define MT256 5             // GEMM M tiles of 256 rows
#define NT 8                // N tiles of 128

typedef __attribute__((ext_vector_type(8))) short     bf16x8;
typedef __attribute__((ext_vector_type(4))) float     f32x4;
typedef __attribute__((ext_vector_type(4))) unsigned short us4;
typedef __attribute__((ext_vector_type(8))) unsigned short us8;

__device__ __forceinline__ unsigned short f2bf(float x) {
    unsigned u = __float_as_uint(x);
    u += 0x7fffu + ((u >> 16) & 1u);
    return (unsigned short)(u >> 16);
}

__device__ __forceinline__ void gload_lds16(const void* g, void* l) {
    __builtin_amdgcn_global_load_lds(
        (const __attribute__((address_space(1))) unsigned int*)g,
        (__attribute__((address_space(3))) unsigned int*)l, 16, 0, 0);
}

// meta layout (ints): [0]=total, [1..81]=offsets[0..80], [82..82+1039]=row map
#define META_OFFS 1
#define META_MAP  82

// ---- tiny: prefix-sum of box counts + compacted-row -> source-row map
__global__ __launch_bounds__(256) void prefix_kernel(const int* __restrict__ nb,
                                                     int* __restrict__ meta)
{
    __shared__ int off[NBT + 1];
    const int t = threadIdx.x;
    if (t == 0) {
        int acc = 0;
        for (int i = 0; i < NBT; ++i) { off[i] = acc; acc += nb[i]; }
        off[NBT] = acc;
        meta[0] = acc;
    }
    __syncthreads();
    if (t < NBT + 1) meta[META_OFFS + t] = off[t];
    for (int f = t; f < NBT * MAXN; f += 256) {
        const int bt = f / MAXN, n = f % MAXN;
        if (n < off[bt + 1] - off[bt]) meta[META_MAP + off[bt] + n] = f;
    }
}

// ---- pack A (compacted rows) fp32 -> bf16 tile images [bm128][it][quad][m][8]
__global__ __launch_bounds__(256) void pack_a(const float* __restrict__ A,
                                              const int* __restrict__ meta,
                                              unsigned short* __restrict__ out)
{
    const int bm = blockIdx.x, it = blockIdx.y;
    const int total = meta[0];
    if (bm * 128 >= total) return;
    __shared__ __attribute__((aligned(16))) unsigned short T[4][128][8];
    const int t = threadIdx.x, k0 = it * 32;
#pragma unroll
    for (int i = 0; i < 4; ++i) {
        const int f  = t + i * 256;
        const int m  = f >> 3;
        const int kp = (f & 7) * 4;
        const int p  = bm * 128 + m;
        float4 v = {0.f, 0.f, 0.f, 0.f};
        if (p < total) {
            const int src = meta[META_MAP + p];
            v = *(const float4*)(A + (size_t)src * K2D + k0 + kp);
        }
        us4 u = { f2bf(v.x), f2bf(v.y), f2bf(v.z), f2bf(v.w) };
        *(us4*)(&T[kp >> 3][m][kp & 7]) = u;
    }
    __syncthreads();
    us8* o = (us8*)(out + (size_t)(bm * KITERS + it) * (TILEB / 2));
    const us8* s = (const us8*)&T[0][0][0];
#pragma unroll
    for (int i = 0; i < 2; ++i) { const int c = t + i * 256; o[c] = s[c]; }
}

// ---- pack W [26400][1024] fp32 -> bf16 tile images [bn][it][quad][n][8]
__global__ __launch_bounds__(256) void pack_b(const float* __restrict__ B,
                                              unsigned short* __restrict__ out)
{
    __shared__ float S[32][129];
    const int bn = blockIdx.x, it = blockIdx.y;
    const int t = threadIdx.x;
#pragma unroll
    for (int i = 0; i < 4; ++i) {
        const int f  = t + i * 256;
        const int kr = f >> 5;
        const int n4 = (f & 31) * 4;
        const float4 v = *(const float4*)(B + (size_t)(it * 32 + kr) * NFB + bn * 128 + n4);
        S[kr][n4 + 0] = v.x; S[kr][n4 + 1] = v.y;
        S[kr][n4 + 2] = v.z; S[kr][n4 + 3] = v.w;
    }
    __syncthreads();
    unsigned short* o = out + (size_t)(bn * KITERS + it) * (TILEB / 2);
#pragma unroll
    for (int i = 0; i < 2; ++i) {
        const int c = t + i * 256;
        const int n = c & 127, q = c >> 7;
        us8 u;
#pragma unroll
        for (int j = 0; j < 8; ++j) u[j] = f2bf(S[q * 8 + j][n]);
        *(us8*)(o + c * 8) = u;
    }
}

// ---- pipelined 256x128 GEMM, 512 thr (8 waves of 64x64), 3 LDS stages.
//      3 load-instrs/wave per tile-issue -> s_waitcnt vmcnt(3) retires 1 tile.
__global__ __launch_bounds__(512, 2) void gemm_pipe(
    const unsigned short* __restrict__ Apack,
    const unsigned short* __restrict__ Bpack,
    float* __restrict__ Cp,
    const int* __restrict__ meta, int kchunk)
{
    __shared__ __attribute__((aligned(16))) unsigned short buf[3][3][4][128][8]; // 72 KB
    const int bm = blockIdx.x, bn = blockIdx.y, s = blockIdx.z;
    const int total = meta[0];
    if (bm * 256 >= total) return;

    const int t = threadIdx.x;
    const int wave = t >> 6, lane = t & 63;
    const int quad = lane >> 4, l16 = lane & 15;
    const int wmq = wave & 3;            // A quadrant 0..3 (rows wmq*64)
    const int asel = wmq >> 1;           // which 128-row A image
    const int wm128 = (wmq & 1) * 64;    // row base within image
    const int wn = (wave >> 2) * 64;
    const int it0 = s * kchunk;
    const int it1 = min(KITERS, it0 + kchunk);   // both multiples of 3

    f32x4 acc[4][4] = {};

    if (it0 < it1) {
        const int itlast = it1 - 1;
        const char* A0 = (const char*)Apack + (size_t)(2 * bm) * KITERS * TILEB;
        const char* A1 = (const char*)Apack + (size_t)(2 * bm + 1) * KITERS * TILEB;
        const char* Bb = (const char*)Bpack + (size_t)bn * KITERS * TILEB;
        const int go = t * 16;            // byte offset within an 8 KB image
        const int lo = wave * 1024;       // wave-uniform LDS base within image

#define ISSUE(IT, ST) do {                                                     \
    const size_t o_ = (size_t)(IT) * TILEB;                                    \
    gload_lds16(A0 + o_ + go, (char*)&buf[ST][0] + lo);                        \
    gload_lds16(A1 + o_ + go, (char*)&buf[ST][1] + lo);                        \
    gload_lds16(Bb + o_ + go, (char*)&buf[ST][2] + lo);                        \
} while (0)

        ISSUE(it0, 0);
        { const int itp = min(it0 + 1, itlast); ISSUE(itp, 1); }

#define STEP(ITV, CUR, DST) do {                                               \
    asm volatile("" ::: "memory");                                             \
    __builtin_amdgcn_s_waitcnt(0x1F73); /* vmcnt(3) */                         \
    __builtin_amdgcn_s_barrier();                                              \
    asm volatile("" ::: "memory");                                             \
    int itn = (ITV) + 2; itn = itn > itlast ? itlast : itn;                    \
    ISSUE(itn, DST);                                                           \
    bf16x8 af[4], bfr[4];                                                      \
    _Pragma("unroll")                                                          \
    for (int x = 0; x < 4; ++x) {                                              \
        af[x]  = *(const bf16x8*)(&buf[CUR][asel][quad][wm128 + x * 16 + l16][0]); \
        bfr[x] = *(const bf16x8*)(&buf[CUR][2][quad][wn + x * 16 + l16][0]);   \
    }                                                                          \
    _Pragma("unroll")                                                          \
    for (int x = 0; x < 4; ++x)                                                \
        _Pragma("unroll")                                                      \
        for (int y = 0; y < 4; ++y)                                            \
            acc[x][y] = __builtin_amdgcn_mfma_f32_16x16x32_bf16(               \
                af[x], bfr[y], acc[x][y], 0, 0, 0);                            \
} while (0)

        for (int it = it0; it < it1; it += 3) {
            STEP(it,     0, 2);
            STEP(it + 1, 1, 0);
            STEP(it + 2, 2, 1);
        }
#undef STEP
#undef ISSUE
    }

    // C write; rows >= total are garbage but never read. Guard vs 1040 only.
#pragma unroll
    for (int x = 0; x < 4; ++x) {
        const int rowb = bm * 256 + wmq * 64 + x * 16 + quad * 4;
#pragma unroll
        for (int y = 0; y < 4; ++y) {
            const int col = bn * 128 + wn + y * 16 + l16;
#pragma unroll
            for (int r = 0; r < 4; ++r) {
                const int rr = rowb + r;
                if (rr < MTOT)
                    Cp[((size_t)s * MTOT + rr) * NFB + col] = acc[x][y][r];
            }
        }
    }
}

// ---- parallel split-K reduce: one block per compacted row
__global__ __launch_bounds__(256) void reduce_kernel(
    const float* __restrict__ Cp, const float* __restrict__ b_emb,
    float* __restrict__ h, const int* __restrict__ meta, int splitk)
{
    const int row = blockIdx.x;
    if (row >= meta[0]) return;
    const int t = threadIdx.x;
    const size_t base = (size_t)row * NFB + t * 4;
    float4 v = *(const float4*)(Cp + base);
#pragma unroll 4
    for (int s2 = 1; s2 < splitk; ++s2) {
        const float4 w = *(const float4*)(Cp + (size_t)s2 * MTOT * NFB + base);
        v.x += w.x; v.y += w.y; v.z += w.z; v.w += w.w;
    }
    const float4 be = *(const float4*)(b_emb + t * 4);
    v.x = fmaxf(v.x + be.x, 0.f);
    v.y = fmaxf(v.y + be.y, 0.f);
    v.z = fmaxf(v.z + be.z, 0.f);
    v.w = fmaxf(v.w + be.w, 0.f);
    *(float4*)(h + base) = v;
}

// ---- per-frame heads on compacted h
__global__ __launch_bounds__(256) void heads_kernel(
    const float* __restrict__ h,
    const float* __restrict__ w_act,  const float* __restrict__ b_act,
    const float* __restrict__ w_acty, const float* __restrict__ b_acty,
    const int* __restrict__ meta, float* __restrict__ out)
{
    __shared__ __attribute__((aligned(16))) float hs[MAXN][NFB];
    __shared__ float pooled[NFB];
    const int bt = blockIdx.x;
    const int t  = threadIdx.x;
    const int off0 = meta[META_OFFS + bt];
    const int Nb   = meta[META_OFFS + bt + 1] - off0;

    for (int i = 0; i < MAXN; ++i)
        if (i < Nb)
            *(float4*)(&hs[i][t * 4]) =
                *(const float4*)(h + (size_t)(off0 + i) * NFB + t * 4);
    __syncthreads();

    const int wave = t >> 6, lane = t & 63;

    for (int d = wave; d < MAXN * NA; d += 4) {
        const int n = d / NA, a = d % NA;
        if (n < Nb) {
            float sum = 0.f;
            for (int f = lane; f < NFB; f += 64)
                sum += hs[n][f] * w_act[f * NA + a];
#pragma unroll
            for (int o = 32; o > 0; o >>= 1) sum += __shfl_xor(sum, o);
            if (lane == 0) out[bt * (MAXN * NA) + d] = sum + b_act[a];
        } else {
            if (lane == 0) out[bt * (MAXN * NA) + d] = 0.f;
        }
    }

    for (int f = t; f < NFB; f += 256) {
        float m = hs[0][f];
        for (int n2 = 1; n2 < Nb; ++n2) m = fmaxf(m, hs[n2][f]);
        pooled[f] = m;
    }
    __syncthreads();

    for (int g = wave; g < NG; g += 4) {
        float sum = 0.f;
        for (int f = lane; f < NFB; f += 64)
            sum += pooled[f] * w_acty[f * NG + g];
#pragma unroll
        for (int o = 32; o > 0; o >>= 1) sum += __shfl_xor(sum, o);
        if (lane == 0)
            out[NBT * MAXN * NA + bt * NG + g] = sum + b_acty[g];
    }
}

// ======== fallback path (round-1 proven), used only if ws too small ========
__global__ __launch_bounds__(256) void gemm_f32(
    const float* __restrict__ A, const float* __restrict__ B,
    float* __restrict__ Cp, int kchunk)
{
    __shared__ __attribute__((aligned(16))) unsigned short Alds[4][128][8];
    __shared__ __attribute__((aligned(16))) unsigned short Blds[4][128][8];
    const int t = threadIdx.x;
    const int bm = blockIdx.x, bn = blockIdx.y, s = blockIdx.z;
    const int wave = t >> 6, lane = t & 63;
    const int quad = lane >> 4, l16 = lane & 15;
    const int wm = (wave & 1) * 64, wn = (wave >> 1) * 64;
    const int row0 = bm * 128, col0 = bn * 128;
    const int it0 = s * kchunk, it1 = min(KITERS, it0 + kchunk);

    f32x4 acc[4][4] = {};
    for (int it = it0; it < it1; ++it) {
        const int k0 = it * 32;
#pragma unroll
        for (int i = 0; i < 4; ++i) {
            const int f = t + i * 256, m = f >> 3, kp = (f & 7) * 4;
            const int gr = row0 + m;
            float4 v = {0.f, 0.f, 0.f, 0.f};
            if (gr < MTOT) v = *(const float4*)(A + (size_t)gr * K2D + k0 + kp);
            us4 u = { f2bf(v.x), f2bf(v.y), f2bf(v.z), f2bf(v.w) };
            *(us4*)(&Alds[kp >> 3][m][kp & 7]) = u;
        }
#pragma unroll
        for (int i = 0; i < 2; ++i) {
            const int p = t + i * 256, n = p & 127, kq = p >> 7;
            const float* bp = B + (size_t)(k0 + kq * 8) * NFB + (col0 + n);
            us8 u;
#pragma unroll
            for (int j = 0; j < 8; ++j) u[j] = f2bf(bp[(size_t)j * NFB]);
            *(us8*)(&Blds[kq][n][0]) = u;
        }
        __syncthreads();
        bf16x8 af[4], bfr[4];
#pragma unroll
        for (int x = 0; x < 4; ++x) {
            af[x]  = *(const bf16x8*)(&Alds[quad][wm + x * 16 + l16][0]);
            bfr[x] = *(const bf16x8*)(&Blds[quad][wn + x * 16 + l16][0]);
        }
#pragma unroll
        for (int x = 0; x < 4; ++x)
#pragma unroll
            for (int y = 0; y < 4; ++y)
                acc[x][y] = __builtin_amdgcn_mfma_f32_16x16x32_bf16(
                    af[x], bfr[y], acc[x][y], 0, 0, 0);
        __syncthreads();
    }
#pragma unroll
    for (int x = 0; x < 4; ++x) {
        const int rowb = row0 + wm + x * 16 + quad * 4;
#pragma unroll
        for (int y = 0; y < 4; ++y) {
            const int col = col0 + wn + y * 16 + l16;
#pragma unroll
            for (int r = 0; r < 4; ++r) {
                const int rr = rowb + r;
                if (rr < MTOT)
                    Cp[((size_t)s * MTOT + rr) * NFB + col] = acc[x][y][r];
            }
        }
    }
}

__global__ __launch_bounds__(256) void finalize_fallback(
    const float* __restrict__ Cp, const float* __restrict__ b_emb,
    const float* __restrict__ w_act, const float* __restrict__ b_act,
    const float* __restrict__ w_acty, const float* __restrict__ b_acty,
    const int* __restrict__ bboxes_num, float* __restrict__ out, int splitk)
{
    __shared__ __attribute__((aligned(16))) float h[MAXN][NFB];
    __shared__ float pooled[NFB];
    const int bt = blockIdx.x;
    const int t  = threadIdx.x;
    const int Nb = bboxes_num[bt];

    for (int i = 0; i < MAXN; ++i) {
        const int flat = i * 256 + t;
        const int row  = flat >> 8;
        const int f4   = flat & 255;
        const size_t base = ((size_t)(bt * MAXN + row)) * NFB + f4 * 4;
        float4 v = *(const float4*)(Cp + base);
        for (int s2 = 1; s2 < splitk; ++s2) {
            const float4 w = *(const float4*)(Cp + (size_t)s2 * MTOT * NFB + base);
            v.x += w.x; v.y += w.y; v.z += w.z; v.w += w.w;
        }
        const float4 be = *(const float4*)(b_emb + f4 * 4);
        v.x = fmaxf(v.x + be.x, 0.f);
        v.y = fmaxf(v.y + be.y, 0.f);
        v.z = fmaxf(v.z + be.z, 0.f);
        v.w = fmaxf(v.w + be.w, 0.f);
        *(float4*)(&h[row][f4 * 4]) = v;
    }
    __syncthreads();
    const int wave = t >> 6, lane = t & 63;
    for (int d = wave; d < MAXN * NA; d += 4) {
        const int n = d / NA, a = d % NA;
        float sum = 0.f;
        for (int f = lane; f < NFB; f += 64)
            sum += h[n][f] * w_act[f * NA + a];
#pragma unroll
        for (int o = 32; o > 0; o >>= 1) sum += __shfl_xor(sum, o);
        if (lane == 0)
            out[bt * (MAXN * NA) + d] = (n < Nb) ? (sum + b_act[a]) : 0.f;
    }
    for (int f = t; f < NFB; f += 256) {
        float m = h[0][f];
        for (int n2 = 1; n2 < Nb; ++n2) m = fmaxf(m, h[n2][f]);
        pooled[f] = m;
    }
    __syncthreads();
    for (int g = wave; g < NG; g += 4) {
        float sum = 0.f;
        for (int f = lane; f < NFB; f += 64)
            sum += pooled[f] * w_acty[f * NG + g];
#pragma unroll
        for (int o = 32; o > 0; o >>= 1) sum += __shfl_xor(sum, o);
        if (lane == 0)
            out[NBT * MAXN * NA + bt * NG + g] = sum + b_acty[g];
    }
}

extern "C" void kernel_launch(void* const* d_in, const int* in_sizes, int n_in,
                              void* d_out, int out_size, void* d_ws, size_t ws_size,
                              hipStream_t stream) {
    const float* A      = (const float*)d_in[0];
    const float* W      = (const float*)d_in[1];
    const float* b_emb  = (const float*)d_in[2];
    const float* w_act  = (const float*)d_in[3];
    const float* b_act  = (const float*)d_in[4];
    const float* w_acty = (const float*)d_in[5];
    const float* b_acty = (const float*)d_in[6];
    const int*   bboxes = (const int*)d_in[7];
    float* out = (float*)d_out;

    const size_t PACKA = (size_t)MT128 * KITERS * TILEB;  // 60,825,600 B
    const size_t PACKB = (size_t)NT * KITERS * TILEB;     // 54,067,200 B
    const size_t PART  = (size_t)MTOT * NFB * 4;          //  4,259,840 B
    const size_t METAB = 8192;

    if (ws_size >= PACKA + PACKB + 5 * PART + METAB) {
        int splitk = (int)((ws_size - PACKA - PACKB - PART - METAB) / PART);
        if (splitk > 16) splitk = 16;
        // kchunk: multiple of 3 so the 3-step pipeline unroll divides every chunk
        const int kchunk = ((KITERS + 3 * splitk - 1) / (3 * splitk)) * 3;

        unsigned short* Ap = (unsigned short*)d_ws;
        unsigned short* Bp = (unsigned short*)((char*)d_ws + PACKA);
        float* Cp = (float*)((char*)d_ws + PACKA + PACKB);
        float* h  = (float*)((char*)d_ws + PACKA + PACKB + (size_t)splitk * PART);
        int* meta = (int*)((char*)d_ws + PACKA + PACKB + (size_t)(splitk + 1) * PART);

        prefix_kernel<<<1, 256, 0, stream>>>(bboxes, meta);
        pack_a<<<dim3(MT128, KITERS), 256, 0, stream>>>(A, meta, Ap);
        pack_b<<<dim3(NT, KITERS), 256, 0, stream>>>(W, Bp);
        gemm_pipe<<<dim3(MT256, NT, splitk), 512, 0, stream>>>(Ap, Bp, Cp, meta, kchunk);
        reduce_kernel<<<MTOT, 256, 0, stream>>>(Cp, b_emb, h, meta, splitk);
        heads_kernel<<<NBT, 256, 0, stream>>>(h, w_act, b_act, w_acty, b_acty,
                                              meta, out);
    } else {
        float* Cp = (float*)d_ws;  // needs 17 MB
        gemm_f32<<<dim3(MT128, NT, 4), 256, 0, stream>>>(A, W, Cp, 207);
        finalize_fallback<<<NBT, 256, 0, stream>>>(Cp, b_emb, w_act, b_act,
                                                   w_acty, b_acty, bboxes, out, 4);
    }
}

// Round 5
// 354.757 us; speedup vs baseline: 2.1279x; 1.0547x over previous
//
#include <hip/hip_runtime.h>

#define K2D 26400
#define NFB 1024
#define NBT 80
#define MAXN 13
#define MTOT (NBT * MAXN)   // 1040
#define NA 6
#define NG 5
#define KITERS 825          // K2D / 32
#define TILEB 8192          // bytes of one packed 128x32 bf16 tile image
#define AIMG 10             // A pack images of 128 rows (covers 1280 >= 1040)
#define NT128 8             // B pack images (128 cols each)
#define MT256 5             // GEMM M tiles of 256
#define NT256 4             // GEMM N tiles of 256

typedef __attribute__((ext_vector_type(8))) short     bf16x8;
typedef __attribute__((ext_vector_type(4))) float     f32x4;
typedef __attribute__((ext_vector_type(4))) unsigned short us4;
typedef __attribute__((ext_vector_type(8))) unsigned short us8;

__device__ __forceinline__ unsigned short f2bf(float x) {
    unsigned u = __float_as_uint(x);
    u += 0x7fffu + ((u >> 16) & 1u);
    return (unsigned short)(u >> 16);
}

__device__ __forceinline__ void gload_lds16(const void* g, void* l) {
    __builtin_amdgcn_global_load_lds(
        (const __attribute__((address_space(1))) unsigned int*)g,
        (__attribute__((address_space(3))) unsigned int*)l, 16, 0, 0);
}

// meta layout (ints): [0]=total, [1..81]=offsets[0..80], [82..82+1039]=row map
#define META_OFFS 1
#define META_MAP  82

// ---- parallel prefix of box counts + compacted-row -> source-row map
__global__ __launch_bounds__(256) void prefix_kernel(const int* __restrict__ nb,
                                                     int* __restrict__ meta)
{
    __shared__ int a[128];
    const int t = threadIdx.x;
    if (t < 128) a[t] = (t < NBT) ? nb[t] : 0;
    __syncthreads();
#pragma unroll
    for (int s = 1; s < 128; s <<= 1) {       // Hillis-Steele inclusive scan
        int v = 0;
        if (t < 128 && t >= s) v = a[t - s];
        __syncthreads();
        if (t < 128) a[t] += v;
        __syncthreads();
    }
    if (t == 0) { meta[0] = a[NBT - 1]; meta[META_OFFS] = 0; }
    if (t < NBT) meta[META_OFFS + t + 1] = a[t];
    for (int f = t; f < NBT * MAXN; f += 256) {
        const int bt = f / MAXN, n = f % MAXN;
        const int o0 = bt ? a[bt - 1] : 0;
        if (n < a[bt] - o0) meta[META_MAP + o0 + n] = f;
    }
}

// ---- pack A (compacted rows) fp32 -> bf16 tile images [img][it][quad][m][8]
__global__ __launch_bounds__(256) void pack_a(const float* __restrict__ A,
                                              const int* __restrict__ meta,
                                              unsigned short* __restrict__ out)
{
    const int bm = blockIdx.x, it = blockIdx.y;
    const int total = meta[0];
    if (bm * 128 >= total) return;   // untouched images only feed rows >= total
    __shared__ __attribute__((aligned(16))) unsigned short T[4][128][8];
    const int t = threadIdx.x, k0 = it * 32;
#pragma unroll
    for (int i = 0; i < 4; ++i) {
        const int f  = t + i * 256;
        const int m  = f >> 3;
        const int kp = (f & 7) * 4;
        const int p  = bm * 128 + m;
        float4 v = {0.f, 0.f, 0.f, 0.f};
        if (p < total) {
            const int src = meta[META_MAP + p];
            v = *(const float4*)(A + (size_t)src * K2D + k0 + kp);
        }
        us4 u = { f2bf(v.x), f2bf(v.y), f2bf(v.z), f2bf(v.w) };
        *(us4*)(&T[kp >> 3][m][kp & 7]) = u;
    }
    __syncthreads();
    us8* o = (us8*)(out + (size_t)(bm * KITERS + it) * (TILEB / 2));
    const us8* s = (const us8*)&T[0][0][0];
#pragma unroll
    for (int i = 0; i < 2; ++i) { const int c = t + i * 256; o[c] = s[c]; }
}

// ---- pack W -> bf16 tile images, LDS-free: strided coalesced reads, packed store
__global__ __launch_bounds__(256) void pack_b(const float* __restrict__ B,
                                              unsigned short* __restrict__ out)
{
    const int bn = blockIdx.x, it = blockIdx.y;
    const int t = threadIdx.x;
    unsigned short* o = out + (size_t)(bn * KITERS + it) * (TILEB / 2);
#pragma unroll
    for (int i = 0; i < 2; ++i) {
        const int c = t + i * 256;          // c = quad*128 + n
        const int n = c & 127, q = c >> 7;
        const float* bp = B + (size_t)(it * 32 + q * 8) * NFB + bn * 128 + n;
        float v[8];
#pragma unroll
        for (int j = 0; j < 8; ++j) v[j] = bp[(size_t)j * NFB];
        us8 u;
#pragma unroll
        for (int j = 0; j < 8; ++j) u[j] = f2bf(v[j]);
        *(us8*)(o + c * 8) = u;
    }
}

// ---- pipelined 256x256 GEMM, 512 thr (8 waves of 64x128), 3 LDS stages.
//      4 load-instrs/wave per tile-issue -> s_waitcnt vmcnt(4) retires 1 tile.
__global__ __launch_bounds__(512, 2) void gemm_pipe(
    const unsigned short* __restrict__ Apack,
    const unsigned short* __restrict__ Bpack,
    float* __restrict__ Cp,
    const int* __restrict__ meta, int kchunk)
{
    __shared__ __attribute__((aligned(16))) unsigned short buf[3][4][4][128][8]; // 96 KB
    const int bn = blockIdx.x, s = blockIdx.y, bm = blockIdx.z;
    const int total = meta[0];
    if (bm * 256 >= total) return;

    const int t = threadIdx.x;
    const int wave = t >> 6, lane = t & 63;
    const int quad = lane >> 4, l16 = lane & 15;
    const int wmq = wave & 3;            // row quadrant (64 rows each)
    const int asel = wmq >> 1;           // A image 0/1
    const int wm128 = (wmq & 1) * 64;    // row base within A image
    const int bsel = wave >> 2;          // B image 0/1 (128 cols each)
    const int it0 = s * kchunk;
    const int it1 = min(KITERS, it0 + kchunk);   // kchunk%3==0, 825%3==0

    f32x4 acc[4][8] = {};

    {
        const int itlast = it1 - 1;
        const char* A0 = (const char*)Apack + (size_t)(2 * bm) * KITERS * TILEB;
        const char* A1 = (const char*)Apack + (size_t)(2 * bm + 1) * KITERS * TILEB;
        const char* B0 = (const char*)Bpack + (size_t)(2 * bn) * KITERS * TILEB;
        const char* B1 = (const char*)Bpack + (size_t)(2 * bn + 1) * KITERS * TILEB;
        const int go = t * 16;            // byte offset within an 8 KB image
        const int lo = wave * 1024;       // wave-uniform LDS base within image

#define ISSUE(IT, ST) do {                                                     \
    const size_t o_ = (size_t)(IT) * TILEB;                                    \
    gload_lds16(A0 + o_ + go, (char*)&buf[ST][0] + lo);                        \
    gload_lds16(A1 + o_ + go, (char*)&buf[ST][1] + lo);                        \
    gload_lds16(B0 + o_ + go, (char*)&buf[ST][2] + lo);                        \
    gload_lds16(B1 + o_ + go, (char*)&buf[ST][3] + lo);                        \
} while (0)

        ISSUE(it0, 0);
        { const int itp = min(it0 + 1, itlast); ISSUE(itp, 1); }

#define STEP(ITV, CUR, DST) do {                                               \
    asm volatile("" ::: "memory");                                             \
    __builtin_amdgcn_s_waitcnt(0xF74); /* vmcnt(4) */                          \
    __builtin_amdgcn_s_barrier();                                              \
    asm volatile("" ::: "memory");                                             \
    int itn = (ITV) + 2; itn = itn > itlast ? itlast : itn;                    \
    ISSUE(itn, DST);                                                           \
    bf16x8 af[4], bfr[8];                                                      \
    _Pragma("unroll")                                                          \
    for (int x = 0; x < 4; ++x)                                                \
        af[x] = *(const bf16x8*)(&buf[CUR][asel][quad][wm128 + x * 16 + l16][0]); \
    _Pragma("unroll")                                                          \
    for (int y = 0; y < 8; ++y)                                                \
        bfr[y] = *(const bf16x8*)(&buf[CUR][2 + bsel][quad][y * 16 + l16][0]); \
    _Pragma("unroll")                                                          \
    for (int x = 0; x < 4; ++x)                                                \
        _Pragma("unroll")                                                      \
        for (int y = 0; y < 8; ++y)                                            \
            acc[x][y] = __builtin_amdgcn_mfma_f32_16x16x32_bf16(               \
                af[x], bfr[y], acc[x][y], 0, 0, 0);                            \
} while (0)

        for (int it = it0; it < it1; it += 3) {
            STEP(it,     0, 2);
            STEP(it + 1, 1, 0);
            STEP(it + 2, 2, 1);
        }
#undef STEP
#undef ISSUE
    }

    // C write; rows >= total are garbage but never read downstream.
#pragma unroll
    for (int x = 0; x < 4; ++x) {
        const int rowb = bm * 256 + wmq * 64 + x * 16 + quad * 4;
#pragma unroll
        for (int y = 0; y < 8; ++y) {
            const int col = bn * 256 + bsel * 128 + y * 16 + l16;
#pragma unroll
            for (int r = 0; r < 4; ++r) {
                const int rr = rowb + r;
                if (rr < MTOT)
                    Cp[((size_t)s * MTOT + rr) * NFB + col] = acc[x][y][r];
            }
        }
    }
}

// ---- parallel split-K reduce: one block per compacted row
__global__ __launch_bounds__(256) void reduce_kernel(
    const float* __restrict__ Cp, const float* __restrict__ b_emb,
    float* __restrict__ h, const int* __restrict__ meta, int splitk)
{
    const int row = blockIdx.x;
    if (row >= meta[0]) return;
    const int t = threadIdx.x;
    const size_t base = (size_t)row * NFB + t * 4;
    float4 v = *(const float4*)(Cp + base);
#pragma unroll 4
    for (int s2 = 1; s2 < splitk; ++s2) {
        const float4 w = *(const float4*)(Cp + (size_t)s2 * MTOT * NFB + base);
        v.x += w.x; v.y += w.y; v.z += w.z; v.w += w.w;
    }
    const float4 be = *(const float4*)(b_emb + t * 4);
    v.x = fmaxf(v.x + be.x, 0.f);
    v.y = fmaxf(v.y + be.y, 0.f);
    v.z = fmaxf(v.z + be.z, 0.f);
    v.w = fmaxf(v.w + be.w, 0.f);
    *(float4*)(h + base) = v;
}

// ---- per-frame heads on compacted h
__global__ __launch_bounds__(256) void heads_kernel(
    const float* __restrict__ h,
    const float* __restrict__ w_act,  const float* __restrict__ b_act,
    const float* __restrict__ w_acty, const float* __restrict__ b_acty,
    const int* __restrict__ meta, float* __restrict__ out)
{
    __shared__ __attribute__((aligned(16))) float hs[MAXN][NFB];
    __shared__ float pooled[NFB];
    const int bt = blockIdx.x;
    const int t  = threadIdx.x;
    const int off0 = meta[META_OFFS + bt];
    const int Nb   = meta[META_OFFS + bt + 1] - off0;

    for (int i = 0; i < MAXN; ++i)
        if (i < Nb)
            *(float4*)(&hs[i][t * 4]) =
                *(const float4*)(h + (size_t)(off0 + i) * NFB + t * 4);
    __syncthreads();

    const int wave = t >> 6, lane = t & 63;

    for (int d = wave; d < MAXN * NA; d += 4) {
        const int n = d / NA, a = d % NA;
        if (n < Nb) {
            float sum = 0.f;
            for (int f = lane; f < NFB; f += 64)
                sum += hs[n][f] * w_act[f * NA + a];
#pragma unroll
            for (int o = 32; o > 0; o >>= 1) sum += __shfl_xor(sum, o);
            if (lane == 0) out[bt * (MAXN * NA) + d] = sum + b_act[a];
        } else {
            if (lane == 0) out[bt * (MAXN * NA) + d] = 0.f;
        }
    }

    for (int f = t; f < NFB; f += 256) {
        float m = hs[0][f];
        for (int n2 = 1; n2 < Nb; ++n2) m = fmaxf(m, hs[n2][f]);
        pooled[f] = m;
    }
    __syncthreads();

    for (int g = wave; g < NG; g += 4) {
        float sum = 0.f;
        for (int f = lane; f < NFB; f += 64)
            sum += pooled[f] * w_acty[f * NG + g];
#pragma unroll
        for (int o = 32; o > 0; o >>= 1) sum += __shfl_xor(sum, o);
        if (lane == 0)
            out[NBT * MAXN * NA + bt * NG + g] = sum + b_acty[g];
    }
}

// ======== fallback path (round-1 proven), used only if ws too small ========
__global__ __launch_bounds__(256) void gemm_f32(
    const float* __restrict__ A, const float* __restrict__ B,
    float* __restrict__ Cp, int kchunk)
{
    __shared__ __attribute__((aligned(16))) unsigned short Alds[4][128][8];
    __shared__ __attribute__((aligned(16))) unsigned short Blds[4][128][8];
    const int t = threadIdx.x;
    const int bm = blockIdx.x, bn = blockIdx.y, s = blockIdx.z;
    const int wave = t >> 6, lane = t & 63;
    const int quad = lane >> 4, l16 = lane & 15;
    const int wm = (wave & 1) * 64, wn = (wave >> 1) * 64;
    const int row0 = bm * 128, col0 = bn * 128;
    const int it0 = s * kchunk, it1 = min(KITERS, it0 + kchunk);

    f32x4 acc[4][4] = {};
    for (int it = it0; it < it1; ++it) {
        const int k0 = it * 32;
#pragma unroll
        for (int i = 0; i < 4; ++i) {
            const int f = t + i * 256, m = f >> 3, kp = (f & 7) * 4;
            const int gr = row0 + m;
            float4 v = {0.f, 0.f, 0.f, 0.f};
            if (gr < MTOT) v = *(const float4*)(A + (size_t)gr * K2D + k0 + kp);
            us4 u = { f2bf(v.x), f2bf(v.y), f2bf(v.z), f2bf(v.w) };
            *(us4*)(&Alds[kp >> 3][m][kp & 7]) = u;
        }
#pragma unroll
        for (int i = 0; i < 2; ++i) {
            const int p = t + i * 256, n = p & 127, kq = p >> 7;
            const float* bp = B + (size_t)(k0 + kq * 8) * NFB + (col0 + n);
            us8 u;
#pragma unroll
            for (int j = 0; j < 8; ++j) u[j] = f2bf(bp[(size_t)j * NFB]);
            *(us8*)(&Blds[kq][n][0]) = u;
        }
        __syncthreads();
        bf16x8 af[4], bfr[4];
#pragma unroll
        for (int x = 0; x < 4; ++x) {
            af[x]  = *(const bf16x8*)(&Alds[quad][wm + x * 16 + l16][0]);
            bfr[x] = *(const bf16x8*)(&Blds[quad][wn + x * 16 + l16][0]);
        }
#pragma unroll
        for (int x = 0; x < 4; ++x)
#pragma unroll
            for (int y = 0; y < 4; ++y)
                acc[x][y] = __builtin_amdgcn_mfma_f32_16x16x32_bf16(
                    af[x], bfr[y], acc[x][y], 0, 0, 0);
        __syncthreads();
    }
#pragma unroll
    for (int x = 0; x < 4; ++x) {
        const int rowb = row0 + wm + x * 16 + quad * 4;
#pragma unroll
        for (int y = 0; y < 4; ++y) {
            const int col = col0 + wn + y * 16 + l16;
#pragma unroll
            for (int r = 0; r < 4; ++r) {
                const int rr = rowb + r;
                if (rr < MTOT)
                    Cp[((size_t)s * MTOT + rr) * NFB + col] = acc[x][y][r];
            }
        }
    }
}

__global__ __launch_bounds__(256) void finalize_fallback(
    const float* __restrict__ Cp, const float* __restrict__ b_emb,
    const float* __restrict__ w_act, const float* __restrict__ b_act,
    const float* __restrict__ w_acty, const float* __restrict__ b_acty,
    const int* __restrict__ bboxes_num, float* __restrict__ out, int splitk)
{
    __shared__ __attribute__((aligned(16))) float h[MAXN][NFB];
    __shared__ float pooled[NFB];
    const int bt = blockIdx.x;
    const int t  = threadIdx.x;
    const int Nb = bboxes_num[bt];

    for (int i = 0; i < MAXN; ++i) {
        const int flat = i * 256 + t;
        const int row  = flat >> 8;
        const int f4   = flat & 255;
        const size_t base = ((size_t)(bt * MAXN + row)) * NFB + f4 * 4;
        float4 v = *(const float4*)(Cp + base);
        for (int s2 = 1; s2 < splitk; ++s2) {
            const float4 w = *(const float4*)(Cp + (size_t)s2 * MTOT * NFB + base);
            v.x += w.x; v.y += w.y; v.z += w.z; v.w += w.w;
        }
        const float4 be = *(const float4*)(b_emb + f4 * 4);
        v.x = fmaxf(v.x + be.x, 0.f);
        v.y = fmaxf(v.y + be.y, 0.f);
        v.z = fmaxf(v.z + be.z, 0.f);
        v.w = fmaxf(v.w + be.w, 0.f);
        *(float4*)(&h[row][f4 * 4]) = v;
    }
    __syncthreads();
    const int wave = t >> 6, lane = t & 63;
    for (int d = wave; d < MAXN * NA; d += 4) {
        const int n = d / NA, a = d % NA;
        float sum = 0.f;
        for (int f = lane; f < NFB; f += 64)
            sum += h[n][f] * w_act[f * NA + a];
#pragma unroll
        for (int o = 32; o > 0; o >>= 1) sum += __shfl_xor(sum, o);
        if (lane == 0)
            out[bt * (MAXN * NA) + d] = (n < Nb) ? (sum + b_act[a]) : 0.f;
    }
    for (int f = t; f < NFB; f += 256) {
        float m = h[0][f];
        for (int n2 = 1; n2 < Nb; ++n2) m = fmaxf(m, h[n2][f]);
        pooled[f] = m;
    }
    __syncthreads();
    for (int g = wave; g < NG; g += 4) {
        float sum = 0.f;
        for (int f = lane; f < NFB; f += 64)
            sum += pooled[f] * w_acty[f * NG + g];
#pragma unroll
        for (int o = 32; o > 0; o >>= 1) sum += __shfl_xor(sum, o);
        if (lane == 0)
            out[NBT * MAXN * NA + bt * NG + g] = sum + b_acty[g];
    }
}

extern "C" void kernel_launch(void* const* d_in, const int* in_sizes, int n_in,
                              void* d_out, int out_size, void* d_ws, size_t ws_size,
                              hipStream_t stream) {
    const float* A      = (const float*)d_in[0];
    const float* W      = (const float*)d_in[1];
    const float* b_emb  = (const float*)d_in[2];
    const float* w_act  = (const float*)d_in[3];
    const float* b_act  = (const float*)d_in[4];
    const float* w_acty = (const float*)d_in[5];
    const float* b_acty = (const float*)d_in[6];
    const int*   bboxes = (const int*)d_in[7];
    float* out = (float*)d_out;

    const size_t PACKA = (size_t)AIMG * KITERS * TILEB;   // 67,584,000 B
    const size_t PACKB = (size_t)NT128 * KITERS * TILEB;  // 54,067,200 B
    const size_t PART  = (size_t)MTOT * NFB * 4;          //  4,259,840 B
    const size_t METAB = 8192;

    long avail = (long)ws_size - (long)(PACKA + PACKB + METAB);
    int splitk = (int)(avail / (long)PART);
    if (splitk > 20) splitk = 20;

    if (splitk >= 4) {
        // kchunk: multiple of 3 so the 3-step pipeline divides every chunk
        const int kchunk = ((KITERS + 3 * splitk - 1) / (3 * splitk)) * 3;
        const int nchunks = (KITERS + kchunk - 1) / kchunk;

        unsigned short* Ap = (unsigned short*)d_ws;
        unsigned short* Bp = (unsigned short*)((char*)d_ws + PACKA);
        float* Cp = (float*)((char*)d_ws + PACKA + PACKB);
        int* meta = (int*)((char*)d_ws + PACKA + PACKB + (size_t)splitk * PART);
        float* h  = (float*)d_ws;   // aliases PACKA (dead after gemm)

        prefix_kernel<<<1, 256, 0, stream>>>(bboxes, meta);
        pack_a<<<dim3(AIMG, KITERS), 256, 0, stream>>>(A, meta, Ap);
        pack_b<<<dim3(NT128, KITERS), 256, 0, stream>>>(W, Bp);
        // bm in grid-z: active blocks are linearly first -> balanced dispatch
        gemm_pipe<<<dim3(NT256, nchunks, MT256), 512, 0, stream>>>(Ap, Bp, Cp,
                                                                   meta, kchunk);
        reduce_kernel<<<MTOT, 256, 0, stream>>>(Cp, b_emb, h, meta, nchunks);
        heads_kernel<<<NBT, 256, 0, stream>>>(h, w_act, b_act, w_acty, b_acty,
                                              meta, out);
    } else {
        float* Cp = (float*)d_ws;  // needs 17 MB
        gemm_f32<<<dim3(9, 8, 4), 256, 0, stream>>>(A, W, Cp, 207);
        finalize_fallback<<<NBT, 256, 0, stream>>>(Cp, b_emb, w_act, b_act,
                                                   w_acty, b_acty, bboxes, out, 4);
    }
}